// Round 1
// baseline (502.462 us; speedup 1.0000x reference)
//
#include <hip/hip_runtime.h>
#include <hip/hip_bf16.h>

#define DFEAT 64

// ---------------------------------------------------------------------------
// Kernel 1: degree histogram. deg[i] = #edges with row==i (int atomics).
// ---------------------------------------------------------------------------
__global__ void deg_kernel(const int* __restrict__ row, int E, int* __restrict__ deg) {
    int i = blockIdx.x * blockDim.x + threadIdx.x;
    if (i < E) {
        atomicAdd(&deg[row[i]], 1);
    }
}

// ---------------------------------------------------------------------------
// Kernel 2: dis[i] = deg>0 ? rsqrt(deg) : 0   (in-place int -> float)
// ---------------------------------------------------------------------------
__global__ void dis_kernel(float* __restrict__ buf, int n) {
    int i = blockIdx.x * blockDim.x + threadIdx.x;
    if (i < n) {
        int d = ((const int*)buf)[i];
        buf[i] = (d > 0) ? rsqrtf((float)d) : 0.0f;
    }
}

// ---------------------------------------------------------------------------
// Kernel 3: SpMM scatter. One 64-lane wave per edge; lane f handles feature f.
//   accum[row][f] += dis[col] * feat[col][f]
// (the dis[row] factor is applied in the GEMM epilogue)
// ---------------------------------------------------------------------------
__global__ void spmm_kernel(const int* __restrict__ ei, int E,
                            const float* __restrict__ feat,
                            const float* __restrict__ dis,
                            float* __restrict__ accum) {
    long long gtid = (long long)blockIdx.x * blockDim.x + threadIdx.x;
    int e = (int)(gtid >> 6);
    int lane = threadIdx.x & 63;
    if (e < E) {
        int r = ei[e];        // destination
        int c = ei[E + e];    // source
        float w = dis[c];     // broadcast (same addr across wave)
        float v = w * feat[(long long)c * DFEAT + lane];
        atomicAdd(&accum[(long long)r * DFEAT + lane], v);
    }
}

// ---------------------------------------------------------------------------
// Kernel 4: out[i][j] = relu( (dis[i]*accum[i]) @ W + b )[j]
// One wave per row. W (64x64 fp32 = 16 KB) staged in LDS.
// Lane j holds column j; row fragment broadcast via __shfl over 64 lanes.
// ---------------------------------------------------------------------------
__global__ void gemm_relu_kernel(const float* __restrict__ accum,
                                 const float* __restrict__ dis,
                                 const float* __restrict__ W,
                                 const float* __restrict__ bias,
                                 float* __restrict__ out, int n) {
    __shared__ float sW[DFEAT * DFEAT];
    __shared__ float sb[DFEAT];
    for (int i = threadIdx.x; i < DFEAT * DFEAT; i += blockDim.x) sW[i] = W[i];
    if (threadIdx.x < DFEAT) sb[threadIdx.x] = bias[threadIdx.x];
    __syncthreads();

    int wave = (int)(((long long)blockIdx.x * blockDim.x + threadIdx.x) >> 6);
    int lane = threadIdx.x & 63;
    if (wave < n) {
        float p = dis[wave] * accum[(long long)wave * DFEAT + lane];
        float acc = sb[lane];
#pragma unroll
        for (int k = 0; k < DFEAT; k++) {
            float pk = __shfl(p, k);                 // broadcast p[k] across wave
            acc = fmaf(pk, sW[k * DFEAT + lane], acc);
        }
        out[(long long)wave * DFEAT + lane] = fmaxf(acc, 0.0f);
    }
}

// ---------------------------------------------------------------------------
extern "C" void kernel_launch(void* const* d_in, const int* in_sizes, int n_in,
                              void* d_out, int out_size, void* d_ws, size_t ws_size,
                              hipStream_t stream) {
    const float* feat = (const float*)d_in[0];   // [N, 64] f32
    const int*   ei   = (const int*)d_in[1];     // [2, E] int32 (rows then cols)
    const float* W    = (const float*)d_in[2];   // [64, 64] f32
    const float* bias = (const float*)d_in[3];   // [64] f32
    float* out = (float*)d_out;                  // [N, 64] f32

    int n_nodes = in_sizes[0] / DFEAT;
    int E = in_sizes[1] / 2;

    // workspace layout: [deg/dis: n_nodes f32][accum: n_nodes*64 f32]
    float* deg   = (float*)d_ws;
    float* accum = deg + n_nodes;
    size_t zero_bytes = (size_t)(n_nodes + (long long)n_nodes * DFEAT) * sizeof(float);
    hipMemsetAsync(d_ws, 0, zero_bytes, stream);

    // 1) degrees
    {
        int threads = 256;
        int blocks = (E + threads - 1) / threads;
        deg_kernel<<<blocks, threads, 0, stream>>>(ei, E, (int*)deg);
    }
    // 2) deg^{-1/2}
    {
        int threads = 256;
        int blocks = (n_nodes + threads - 1) / threads;
        dis_kernel<<<blocks, threads, 0, stream>>>(deg, n_nodes);
    }
    // 3) scatter SpMM (one wave per edge)
    {
        long long total_threads = (long long)E * 64;
        int threads = 256;
        long long blocks = (total_threads + threads - 1) / threads;
        spmm_kernel<<<(int)blocks, threads, 0, stream>>>(ei, E, feat, deg, accum);
    }
    // 4) GEMM + bias + relu (one wave per row, 4 waves/block)
    {
        int threads = 256;
        int blocks = (n_nodes + 3) / 4;
        gemm_relu_kernel<<<blocks, threads, 0, stream>>>(accum, deg, W, bias, out, n_nodes);
    }
}

// Round 2
// 329.606 us; speedup vs baseline: 1.5244x; 1.5244x over previous
//
#include <hip/hip_runtime.h>
#include <hip/hip_bf16.h>

#define DFEAT 64
#define SCAN_BLOCK 1024

// ---------------------------------------------------------------------------
// 1) degree histogram (int atomics, 1.25M — cheap)
// ---------------------------------------------------------------------------
__global__ void hist_kernel(const int* __restrict__ row, int E, int* __restrict__ deg) {
    int i = blockIdx.x * blockDim.x + threadIdx.x;
    if (i < E) atomicAdd(&deg[row[i]], 1);
}

// ---------------------------------------------------------------------------
// 2) per-block sums of deg (for two-level exclusive scan)
// ---------------------------------------------------------------------------
__global__ void blocksum_kernel(const int* __restrict__ deg, int n, int* __restrict__ bsum) {
    __shared__ int tmp[SCAN_BLOCK];
    int tid = threadIdx.x;
    int gid = blockIdx.x * SCAN_BLOCK + tid;
    tmp[tid] = (gid < n) ? deg[gid] : 0;
    __syncthreads();
    for (int s = SCAN_BLOCK / 2; s > 0; s >>= 1) {
        if (tid < s) tmp[tid] += tmp[tid + s];
        __syncthreads();
    }
    if (tid == 0) bsum[blockIdx.x] = tmp[0];
}

// ---------------------------------------------------------------------------
// 3) exclusive scan of ~98 block sums (single thread — trivial)
// ---------------------------------------------------------------------------
__global__ void scan_small_kernel(int* __restrict__ bsum, int nb) {
    if (threadIdx.x == 0 && blockIdx.x == 0) {
        int run = 0;
        for (int i = 0; i < nb; i++) { int t = bsum[i]; bsum[i] = run; run += t; }
    }
}

// ---------------------------------------------------------------------------
// 4) row_start = exclusive scan(deg); dis = deg^{-1/2}; deg reset -> cursor
// ---------------------------------------------------------------------------
__global__ void offsets_kernel(int* __restrict__ deg, const int* __restrict__ bsum,
                               int* __restrict__ row_start, float* __restrict__ dis,
                               int n, int E) {
    __shared__ int tmp[SCAN_BLOCK];
    int tid = threadIdx.x;
    int gid = blockIdx.x * SCAN_BLOCK + tid;
    int v = (gid < n) ? deg[gid] : 0;
    tmp[tid] = v;
    __syncthreads();
    // Hillis-Steele inclusive scan over the block
    for (int off = 1; off < SCAN_BLOCK; off <<= 1) {
        int t = (tid >= off) ? tmp[tid - off] : 0;
        __syncthreads();
        tmp[tid] += t;
        __syncthreads();
    }
    int excl = tmp[tid] - v;
    if (gid < n) {
        row_start[gid] = bsum[blockIdx.x] + excl;
        dis[gid] = (v > 0) ? rsqrtf((float)v) : 0.0f;
        deg[gid] = 0;  // reuse as scatter cursor
    }
    if (gid == 0) row_start[n] = E;
}

// ---------------------------------------------------------------------------
// 5) Y[t] = dis[t] * (feat[t] @ W)   — one thread per row, W in LDS (broadcast)
// ---------------------------------------------------------------------------
__global__ void xw_kernel(const float* __restrict__ feat, const float* __restrict__ W,
                          const float* __restrict__ dis, float* __restrict__ Y, int n) {
    __shared__ float4 sW[DFEAT * 16];  // W[k][j] as float4 over j
    for (int i = threadIdx.x; i < DFEAT * 16; i += blockDim.x)
        sW[i] = ((const float4*)W)[i];
    __syncthreads();
    int t = blockIdx.x * blockDim.x + threadIdx.x;
    if (t >= n) return;
    float d = dis[t];
    float4 acc[16];
#pragma unroll
    for (int j = 0; j < 16; j++) acc[j] = make_float4(0.f, 0.f, 0.f, 0.f);
    const float4* x4 = (const float4*)(feat + (size_t)t * DFEAT);
    for (int k4 = 0; k4 < 16; k4++) {
        float4 xv = x4[k4];
        float xs[4] = {xv.x, xv.y, xv.z, xv.w};
#pragma unroll
        for (int kk = 0; kk < 4; kk++) {
            float xk = xs[kk];
            const float4* wrow = &sW[(k4 * 4 + kk) * 16];
#pragma unroll
            for (int j = 0; j < 16; j++) {
                float4 w = wrow[j];
                acc[j].x = fmaf(xk, w.x, acc[j].x);
                acc[j].y = fmaf(xk, w.y, acc[j].y);
                acc[j].z = fmaf(xk, w.z, acc[j].z);
                acc[j].w = fmaf(xk, w.w, acc[j].w);
            }
        }
    }
    float4* Yo = (float4*)(Y + (size_t)t * DFEAT);
#pragma unroll
    for (int j = 0; j < 16; j++) {
        float4 a = acc[j];
        a.x *= d; a.y *= d; a.z *= d; a.w *= d;
        Yo[j] = a;
    }
}

// ---------------------------------------------------------------------------
// 6) scatter edges into CSR order (int atomics on per-row cursors)
// ---------------------------------------------------------------------------
__global__ void scatter_kernel(const int* __restrict__ ei, int E,
                               const int* __restrict__ row_start,
                               int* __restrict__ cursor, int* __restrict__ csr_col) {
    int e = blockIdx.x * blockDim.x + threadIdx.x;
    if (e < E) {
        int r = ei[e];
        int c = ei[E + e];
        int p = row_start[r] + atomicAdd(&cursor[r], 1);
        csr_col[p] = c;
    }
}

// ---------------------------------------------------------------------------
// 7) gather-reduce SpMM + epilogue. One wave per destination row.
//    Wave layout: sub = lane>>4 (edge slot 0..3), f4 = lane&15 (float4 of feat).
//    4 edges in flight per iteration, dwordx4 gathers, shfl-xor reduce.
// ---------------------------------------------------------------------------
__global__ void spmm_csr_kernel(const int* __restrict__ row_start,
                                const int* __restrict__ csr_col,
                                const float* __restrict__ Y,
                                const float* __restrict__ dis,
                                const float* __restrict__ bias,
                                float* __restrict__ out, int n) {
    int wid = (int)(((long long)blockIdx.x * blockDim.x + threadIdx.x) >> 6);
    int lane = threadIdx.x & 63;
    if (wid >= n) return;
    int s = row_start[wid];
    int e = row_start[wid + 1];
    int sub = lane >> 4;
    int f4 = lane & 15;
    float4 acc = make_float4(0.f, 0.f, 0.f, 0.f);
    const float4* Yv = (const float4*)Y;
    for (int base = s; base < e; base += 64) {
        int cnt = min(64, e - base);
        int c = (lane < cnt) ? csr_col[base + lane] : 0;
        for (int i = 0; i < cnt; i += 4) {
            int idx = i + sub;
            int ce = __shfl(c, idx);
            if (idx < cnt) {
                float4 y = Yv[(size_t)ce * 16 + f4];
                acc.x += y.x; acc.y += y.y; acc.z += y.z; acc.w += y.w;
            }
        }
    }
    // reduce across the 4 edge-slots (lane bits 4 and 5)
    acc.x += __shfl_xor(acc.x, 16); acc.y += __shfl_xor(acc.y, 16);
    acc.z += __shfl_xor(acc.z, 16); acc.w += __shfl_xor(acc.w, 16);
    acc.x += __shfl_xor(acc.x, 32); acc.y += __shfl_xor(acc.y, 32);
    acc.z += __shfl_xor(acc.z, 32); acc.w += __shfl_xor(acc.w, 32);
    float dr = dis[wid];
    float4 b = ((const float4*)bias)[f4];
    if (sub == 0) {
        float4 o;
        o.x = fmaxf(fmaf(dr, acc.x, b.x), 0.f);
        o.y = fmaxf(fmaf(dr, acc.y, b.y), 0.f);
        o.z = fmaxf(fmaf(dr, acc.z, b.z), 0.f);
        o.w = fmaxf(fmaf(dr, acc.w, b.w), 0.f);
        ((float4*)out)[(size_t)wid * 16 + f4] = o;
    }
}

// ---------------------------------------------------------------------------
extern "C" void kernel_launch(void* const* d_in, const int* in_sizes, int n_in,
                              void* d_out, int out_size, void* d_ws, size_t ws_size,
                              hipStream_t stream) {
    const float* feat = (const float*)d_in[0];   // [N, 64] f32
    const int*   ei   = (const int*)d_in[1];     // [2, E] int32 (rows then cols)
    const float* W    = (const float*)d_in[2];   // [64, 64] f32
    const float* bias = (const float*)d_in[3];   // [64] f32
    float* out = (float*)d_out;                  // [N, 64] f32

    int n = in_sizes[0] / DFEAT;
    int E = in_sizes[1] / 2;
    int nb = (n + SCAN_BLOCK - 1) / SCAN_BLOCK;

    // workspace layout (ints; every region 16B-aligned):
    int* ws = (int*)d_ws;
    size_t o = 0;
    int*   deg       = ws + o; o += (size_t)n;            // n (also cursor)
    int*   row_start = ws + o; o += (size_t)(n + 4) & ~3; // n+1 padded
    float* dis       = (float*)(ws + o); o += (size_t)n;
    int*   bsum      = ws + o; o += 256;
    int*   csr_col   = ws + o; o += (size_t)(E + 3) & ~3; // E
    float* Y         = (float*)(ws + o);                  // n*64

    hipMemsetAsync(deg, 0, (size_t)n * sizeof(int), stream);

    int eb = (E + 255) / 256;
    hist_kernel<<<eb, 256, 0, stream>>>(ei, E, deg);
    blocksum_kernel<<<nb, SCAN_BLOCK, 0, stream>>>(deg, n, bsum);
    scan_small_kernel<<<1, 64, 0, stream>>>(bsum, nb);
    offsets_kernel<<<nb, SCAN_BLOCK, 0, stream>>>(deg, bsum, row_start, dis, n, E);
    xw_kernel<<<(n + 255) / 256, 256, 0, stream>>>(feat, W, dis, Y, n);
    scatter_kernel<<<eb, 256, 0, stream>>>(ei, E, row_start, deg, csr_col);
    spmm_csr_kernel<<<(n + 3) / 4, 256, 0, stream>>>(row_start, csr_col, Y, dis, bias, out, n);
}